// Round 2
// baseline (74.048 us; speedup 1.0000x reference)
//
#include <hip/hip_runtime.h>
#include <hip/hip_bf16.h>

// Sizes fixed by the problem
#define Bb 4
#define Nn 256
#define Dd 128
#define Hh 8
#define Kk 16
#define HK 128          // H*K
#define BN 1024         // B*N

// Kernel 1: Q = h@Wq, K = h@Wk * K^-0.5, V = h@Wv  (f32 into workspace)
// 128 blocks x 128 threads, each block computes 8 rows so the 192 KB of W
// is read 128x from L2 instead of 1024x.
__global__ __launch_bounds__(128) void qkv_kernel(
    const float* __restrict__ h,
    const float* __restrict__ Wq,
    const float* __restrict__ Wk,
    const float* __restrict__ Wv,
    float* __restrict__ Qw, float* __restrict__ Kw, float* __restrict__ Vw)
{
    __shared__ float hrows[8][Dd];
    const int rb = blockIdx.x;          // rows rb*8 .. rb*8+7
    const int t  = threadIdx.x;         // output column 0..127
    #pragma unroll
    for (int r = 0; r < 8; ++r)
        hrows[r][t] = h[(size_t)(rb * 8 + r) * Dd + t];
    __syncthreads();

    float aq[8], ak[8], av[8];
    #pragma unroll
    for (int r = 0; r < 8; ++r) { aq[r] = 0.f; ak[r] = 0.f; av[r] = 0.f; }

    for (int d = 0; d < Dd; ++d) {
        const float wq = Wq[d * HK + t];
        const float wk = Wk[d * HK + t];
        const float wv = Wv[d * HK + t];
        #pragma unroll
        for (int r = 0; r < 8; ++r) {
            const float hv = hrows[r][d];   // LDS broadcast (free)
            aq[r] = fmaf(hv, wq, aq[r]);
            ak[r] = fmaf(hv, wk, ak[r]);
            av[r] = fmaf(hv, wv, av[r]);
        }
    }
    #pragma unroll
    for (int r = 0; r < 8; ++r) {
        const size_t o = (size_t)(rb * 8 + r) * HK + t;
        Qw[o] = aq[r];
        Kw[o] = ak[r] * 0.25f;              // K^-0.5 = 1/sqrt(16)
        Vw[o] = av[r];
    }
}

// Kernel 2: one block per (b,i). Phase B computes qk[j][h] in LDS, then a
// memory-bound float4 sweep over e_att/e_val with online accumulation.
__global__ __launch_bounds__(256) void attn_kernel(
    const float* __restrict__ e_att,
    const float* __restrict__ e_val,
    const float* __restrict__ mask,
    const float* __restrict__ Qw,
    const float* __restrict__ Kw,
    const float* __restrict__ Vw,
    float* __restrict__ out)
{
    __shared__ float qrow[HK];              // Q[b,i,:,:]
    __shared__ float mrow[Nn];              // mask[b,:]
    __shared__ float buf[3 * 8 * HK];       // 3072 f32; first 2048 double as qk

    const int t  = threadIdx.x;             // 0..255
    const int bi = blockIdx.x;              // b*N + i
    const int b  = bi >> 8;

    if (t < HK) qrow[t] = Qw[(size_t)bi * HK + t];
    mrow[t] = mask[b * Nn + t];
    __syncthreads();

    const float maski = mrow[bi & 255];

    // ---- Phase B: qk[j*8+h] = sum_k Q[b,i,h,k] * Kscaled[b,j,h,k] ----
    float* qk_s = buf;                      // [Nn*Hh] = 2048
    #pragma unroll
    for (int p = 0; p < 8; ++p) {
        const int idx = p * 256 + t;        // 0..2047
        const int j   = idx >> 3;
        const int hh  = idx & 7;
        const float* kp = Kw + (size_t)(b * Nn + j) * HK + hh * Kk;
        const float* qp = qrow + hh * Kk;
        float acc = 0.f;
        #pragma unroll
        for (int k = 0; k < Kk; ++k) acc = fmaf(qp[k], kp[k], acc);
        qk_s[idx] = acc;
    }
    __syncthreads();

    // ---- Phase C: sweep j, float4 (16 B) per lane ----
    const int q32  = t & 31;                // 32 lanes cover one j row (128 f32)
    const int joff = t >> 5;                // 0..7
    const int hk4  = q32 * 4;               // owned hk block
    const int hh   = q32 >> 2;              // head of this hk block

    float acc_d[4] = {0,0,0,0}, acc_v[4] = {0,0,0,0}, acc_e[4] = {0,0,0,0};
    const size_t slice = (size_t)bi * (Nn * HK);

    for (int jb = 0; jb < Nn; jb += 8) {
        const int j = jb + joff;
        const size_t eoff = slice + (size_t)j * HK + hk4;
        const float4 ea = *(const float4*)(e_att + eoff);
        const float4 ev = *(const float4*)(e_val + eoff);
        const float4 v4 = *(const float4*)(Vw + (size_t)(b * Nn + j) * HK + hk4);

        const float qk = qk_s[(j << 3) + hh];
        const float m  = maski * mrow[j];
        const float m2 = m * m;

        const float eaf[4] = {ea.x, ea.y, ea.z, ea.w};
        const float evf[4] = {ev.x, ev.y, ev.z, ev.w};
        const float vv[4]  = {v4.x, v4.y, v4.z, v4.w};

        #pragma unroll
        for (int l = 0; l < 4; ++l) {
            float x = qk + eaf[l];
            x = fminf(fmaxf(x, -5.f), 5.f);
            const float e = __expf(x);
            acc_d[l] = fmaf(e, m, acc_d[l]);   // denom uses scores*m
            const float s2 = e * m2;           // numerator uses scores*m^2
            acc_v[l] = fmaf(s2, vv[l], acc_v[l]);
            acc_e[l] = fmaf(s2, evf[l], acc_e[l]);
        }
    }
    __syncthreads();   // qk_s reads done; reuse buffer for reduction

    // ---- Phase D: reduce 8 j-partials per hk ----
    #pragma unroll
    for (int l = 0; l < 4; ++l) {
        buf[0 * 1024 + joff * HK + hk4 + l] = acc_d[l];
        buf[1 * 1024 + joff * HK + hk4 + l] = acc_v[l];
        buf[2 * 1024 + joff * HK + hk4 + l] = acc_e[l];
    }
    __syncthreads();

    if (t < HK) {
        float D = 0.f, OV = 0.f, OE = 0.f;
        #pragma unroll
        for (int p = 0; p < 8; ++p) {
            D  += buf[0 * 1024 + p * HK + t];
            OV += buf[1 * 1024 + p * HK + t];
            OE += buf[2 * 1024 + p * HK + t];
        }
        out[(size_t)bi * HK + t] = (OV + OE) / fmaxf(D, 1e-6f);
    }
}

extern "C" void kernel_launch(void* const* d_in, const int* in_sizes, int n_in,
                              void* d_out, int out_size, void* d_ws, size_t ws_size,
                              hipStream_t stream) {
    const float* h     = (const float*)d_in[0];
    const float* e_att = (const float*)d_in[1];
    const float* e_val = (const float*)d_in[2];
    const float* mask  = (const float*)d_in[3];
    const float* Wq    = (const float*)d_in[4];
    const float* Wk    = (const float*)d_in[5];
    const float* Wv    = (const float*)d_in[6];
    float* out = (float*)d_out;

    float* Qw = (float*)d_ws;               // 131072 f32
    float* Kw = Qw + (size_t)BN * HK;       // 131072 f32
    float* Vw = Kw + (size_t)BN * HK;       // 131072 f32 (total 1.5 MiB)

    qkv_kernel<<<128, 128, 0, stream>>>(h, Wq, Wk, Wv, Qw, Kw, Vw);
    attn_kernel<<<BN, 256, 0, stream>>>(e_att, e_val, mask, Qw, Kw, Vw, out);
}